// Round 1
// baseline (528.066 us; speedup 1.0000x reference)
//
#include <hip/hip_runtime.h>
#include <math.h>

#define N_NODES 50000
#define N_RELS  500
#define N_EDGE  800000
#define HID     64
#define HEADS   4
#define DH      16
#define LAYERS  2
#define HOPS    3
#define TOPK    10
#define ALPHA   0.15f
#define SLOPE   0.2f

// ---------------------------------------------------------------- CSR build
__global__ void hist_kernel(const int* __restrict__ dst, int* __restrict__ counts) {
    int t = blockIdx.x * 256 + threadIdx.x;
    if (t < N_EDGE) atomicAdd(&counts[dst[t]], 1);
}

// single-block exclusive scan of counts[N_NODES] -> row_ptr[N_NODES+1]
__global__ void scan_kernel(const int* __restrict__ counts, int* __restrict__ row_ptr) {
    __shared__ int wtot[16];
    __shared__ int wpre[16];
    __shared__ int carry_s;
    int t = threadIdx.x;           // 0..1023
    int lane = t & 63, wid = t >> 6;
    if (t == 0) carry_s = 0;
    __syncthreads();
    for (int base = 0; base < N_NODES; base += 4096) {
        int i0 = base + t * 4;
        int x0 = (i0 + 0 < N_NODES) ? counts[i0 + 0] : 0;
        int x1 = (i0 + 1 < N_NODES) ? counts[i0 + 1] : 0;
        int x2 = (i0 + 2 < N_NODES) ? counts[i0 + 2] : 0;
        int x3 = (i0 + 3 < N_NODES) ? counts[i0 + 3] : 0;
        int tsum = x0 + x1 + x2 + x3;
        int v = tsum;
        #pragma unroll
        for (int off = 1; off < 64; off <<= 1) {
            int u = __shfl_up(v, off, 64);
            if (lane >= off) v += u;
        }
        if (lane == 63) wtot[wid] = v;
        __syncthreads();
        if (wid == 0) {
            int wv = (lane < 16) ? wtot[lane] : 0;
            #pragma unroll
            for (int off = 1; off < 16; off <<= 1) {
                int u = __shfl_up(wv, off, 64);
                if (lane >= off) wv += u;
            }
            if (lane < 16) wpre[lane] = wv;   // inclusive over wave totals
        }
        __syncthreads();
        int carry = carry_s;
        int wbase = (wid == 0) ? 0 : wpre[wid - 1];
        int ex = carry + wbase + (v - tsum);  // exclusive prefix of this thread's 4
        if (i0 + 0 < N_NODES) row_ptr[i0 + 0] = ex;
        if (i0 + 1 < N_NODES) row_ptr[i0 + 1] = ex + x0;
        if (i0 + 2 < N_NODES) row_ptr[i0 + 2] = ex + x0 + x1;
        if (i0 + 3 < N_NODES) row_ptr[i0 + 3] = ex + x0 + x1 + x2;
        int chunk_total = wpre[15];
        __syncthreads();
        if (t == 0) carry_s = carry + chunk_total;
        __syncthreads();
    }
    if (t == 0) row_ptr[N_NODES] = carry_s;   // == N_EDGE
}

__global__ void scatter_kernel(const int* __restrict__ src, const int* __restrict__ dst,
                               const int* __restrict__ rel, const int* __restrict__ row_ptr,
                               int* __restrict__ cursor,
                               int* __restrict__ sorted_src, int* __restrict__ sorted_rel,
                               int* __restrict__ sorted_eid) {
    int t = blockIdx.x * 256 + threadIdx.x;
    if (t >= N_EDGE) return;
    int d = dst[t];
    int pos = row_ptr[d] + atomicAdd(&cursor[d], 1);
    sorted_src[pos] = src[t];
    sorted_rel[pos] = rel[t];
    sorted_eid[pos] = t;     // original edge id for the stable-sort tie-break
}

// ---------------------------------------------------------------- dense pieces
// C[n,64] = A[n,64] @ W[64,64], 32 rows per block
__global__ void gemm64(const float* __restrict__ A, const float* __restrict__ W,
                       float* __restrict__ C, int n) {
    __shared__ float Ws[64][64];
    __shared__ float As[32][64];
    int t = threadIdx.x;      // 256
    for (int i = t; i < 64 * 64; i += 256) Ws[i >> 6][i & 63] = W[i];
    int row0 = blockIdx.x * 32;
    for (int i = t; i < 32 * 64; i += 256) {
        int r = i >> 6, c = i & 63;
        int gr = row0 + r;
        As[r][c] = (gr < n) ? A[(size_t)gr * 64 + c] : 0.f;
    }
    __syncthreads();
    int col = t & 63;
    int r0 = t >> 6;
    for (int r = r0; r < 32; r += 4) {
        float acc = 0.f;
        #pragma unroll
        for (int k = 0; k < 64; ++k) acc += As[r][k] * Ws[k][col];
        int gr = row0 + r;
        if (gr < n) C[(size_t)gr * 64 + col] = acc;
    }
}

// s_src[n,h] = dot(feat0[n,h,:], a0[h,:]); s_dst likewise with a1
__global__ void node_scores(const float* __restrict__ feat0, const float* __restrict__ a,
                            float* __restrict__ s_src, float* __restrict__ s_dst) {
    int t = blockIdx.x * 256 + threadIdx.x;
    if (t >= N_NODES * HEADS) return;
    int n = t >> 2, h = t & 3;
    const float* f  = feat0 + (size_t)n * 64 + h * 16;
    const float* a0 = a + h * 16;             // a[0][h][:]
    const float* a1 = a + HEADS * DH + h * 16; // a[1][h][:]
    float ss = 0.f, sd = 0.f;
    #pragma unroll
    for (int d = 0; d < 16; ++d) { float v = f[d]; ss += v * a0[d]; sd += v * a1[d]; }
    s_src[t] = ss; s_dst[t] = sd;
}

// s_rel[r,h] = dot((rel_emb @ W_rel)[r, h*16:...], a2[h,:])  (proj kept in LDS only)
__global__ void rel_scores(const float* __restrict__ rel_emb, const float* __restrict__ Wr,
                           const float* __restrict__ a2, float* __restrict__ s_rel) {
    __shared__ float proj[64];
    int r = blockIdx.x, c = threadIdx.x;   // 64 threads
    float acc = 0.f;
    #pragma unroll
    for (int k = 0; k < 64; ++k) acc += rel_emb[(size_t)r * 64 + k] * Wr[k * 64 + c];
    proj[c] = acc;
    __syncthreads();
    if (c < HEADS) {
        float s = 0.f;
        #pragma unroll
        for (int d = 0; d < 16; ++d) s += proj[c * 16 + d] * a2[c * 16 + d];
        s_rel[r * HEADS + c] = s;
    }
}

// ---------------------------------------------------------------- top-k + softmax
__global__ void topk_kernel(const int* __restrict__ row_ptr,
                            const int* __restrict__ sorted_src, const int* __restrict__ sorted_rel,
                            const int* __restrict__ sorted_eid,
                            const float* __restrict__ s_src, const float* __restrict__ s_dst,
                            const float* __restrict__ s_rel,
                            int* __restrict__ kept_src, float* __restrict__ kept_w,
                            int* __restrict__ kept_cnt) {
    int t = blockIdx.x * 256 + threadIdx.x;
    if (t >= N_NODES * HEADS) return;
    int d = t >> 2, h = t & 3;
    int beg = row_ptr[d], end = row_ptr[d + 1];
    float sdst = s_dst[t];

    float topS[TOPK]; int topI[TOPK]; int topN[TOPK];
    #pragma unroll
    for (int i = 0; i < TOPK; ++i) { topS[i] = -3.4e38f; topI[i] = 0x7fffffff; topN[i] = 0; }

    for (int j = beg; j < end; ++j) {
        int src = sorted_src[j], rel = sorted_rel[j], eid = sorted_eid[j];
        float sc = s_src[src * HEADS + h] + sdst + s_rel[rel * HEADS + h];
        sc = sc > 0.f ? sc : SLOPE * sc;      // leaky relu
        float s = sc; int id = eid; int sn = src;
        #pragma unroll
        for (int i = 0; i < TOPK; ++i) {      // rank by (score desc, edge id asc)
            bool better = (s > topS[i]) || (s == topS[i] && id < topI[i]);
            if (better) {
                float ts = topS[i]; int ti = topI[i]; int tn = topN[i];
                topS[i] = s; topI[i] = id; topN[i] = sn;
                s = ts; id = ti; sn = tn;
            }
        }
    }
    int deg = end - beg;
    int cnt = deg < TOPK ? deg : TOPK;
    float m = (cnt > 0) ? topS[0] : 0.f;
    float w[TOPK]; float den = 0.f;
    #pragma unroll
    for (int i = 0; i < TOPK; ++i) {
        float e = (i < cnt) ? expf(topS[i] - m) : 0.f;
        w[i] = e; den += e;
    }
    float inv = 1.f / (den + 1e-16f);
    #pragma unroll
    for (int i = 0; i < TOPK; ++i) {
        kept_w[(size_t)t * TOPK + i]   = (i < cnt) ? w[i] * inv : 0.f;
        kept_src[(size_t)t * TOPK + i] = topN[i];
    }
    kept_cnt[t] = cnt;
}

// ---------------------------------------------------------------- diffusion hop
// hc_out[n,c] = (1-ALPHA) * sum_k w_k * hc_in[src_k, c] + ALPHA * feat0[n,c]
__global__ void hop_kernel(const float* __restrict__ hc_in, const float* __restrict__ feat0,
                           const int* __restrict__ kept_src, const float* __restrict__ kept_w,
                           const int* __restrict__ kept_cnt, float* __restrict__ hc_out) {
    __shared__ int   ls[4 * HEADS * TOPK];
    __shared__ float lw[4 * HEADS * TOPK];
    __shared__ int   lc[4 * HEADS];
    int tb = threadIdx.x;            // 256 = 4 nodes * 64
    int nb = blockIdx.x * 4;         // first node of this block
    if (tb < 4 * HEADS * TOPK) {
        int idx = nb * HEADS * TOPK + tb;
        ls[tb] = kept_src[idx];
        lw[tb] = kept_w[idx];
    }
    if (tb < 4 * HEADS) lc[tb] = kept_cnt[nb * HEADS + tb];
    __syncthreads();
    int c  = tb & 63;
    int nl = tb >> 6;
    int h  = c >> 4;
    int lbase = nl * HEADS * TOPK + h * TOPK;
    int cnt = lc[nl * HEADS + h];
    float acc = 0.f;
    for (int k = 0; k < cnt; ++k) {
        acc += lw[lbase + k] * hc_in[(size_t)ls[lbase + k] * 64 + c];
    }
    size_t t = (size_t)nb * 64 + tb;
    hc_out[t] = (1.f - ALPHA) * acc + ALPHA * feat0[t];
}

// ---------------------------------------------------------------- epilogues
__global__ void elu_kernel(const float* __restrict__ hc, const float* __restrict__ res,
                           float* __restrict__ out) {
    size_t t = (size_t)blockIdx.x * 256 + threadIdx.x;
    if (t >= (size_t)N_NODES * HID) return;
    float x = hc[t] + res[t];
    out[t] = x > 0.f ? x : (expf(x) - 1.f);
}

__global__ void relout_kernel(const float* __restrict__ rel_emb, const float* __restrict__ Wf,
                              float* __restrict__ out) {
    int r = blockIdx.x, c = threadIdx.x;  // 500 x 64
    float acc = 0.f;
    #pragma unroll
    for (int k = 0; k < 64; ++k) acc += rel_emb[(size_t)r * 64 + k] * Wf[k * 64 + c];
    out[(size_t)r * 64 + c] = acc;
}

// ---------------------------------------------------------------- launch
extern "C" void kernel_launch(void* const* d_in, const int* in_sizes, int n_in,
                              void* d_out, int out_size, void* d_ws, size_t ws_size,
                              hipStream_t stream) {
    (void)in_sizes; (void)n_in; (void)out_size; (void)ws_size;
    const float* ent_emb  = (const float*)d_in[0];
    const float* rel_emb  = (const float*)d_in[1];
    const int*   edge_src = (const int*)d_in[2];
    const int*   edge_dst = (const int*)d_in[3];
    const int*   edge_rel = (const int*)d_in[4];
    const float* W_ent    = (const float*)d_in[5];
    const float* W_rel    = (const float*)d_in[6];
    const float* attn_a   = (const float*)d_in[7];
    const float* res_W    = (const float*)d_in[8];
    const float* fc_rel_w = (const float*)d_in[9];

    char* wp = (char*)d_ws;
    auto alloc = [&](size_t bytes) -> void* {
        void* p = (void*)wp;
        wp += (bytes + 255) & ~(size_t)255;
        return p;
    };
    int*   counts     = (int*)alloc((size_t)N_NODES * 4);
    int*   cursor     = (int*)alloc((size_t)N_NODES * 4);
    int*   row_ptr    = (int*)alloc((size_t)(N_NODES + 1) * 4);
    int*   sorted_src = (int*)alloc((size_t)N_EDGE * 4);
    int*   sorted_rel = (int*)alloc((size_t)N_EDGE * 4);
    int*   sorted_eid = (int*)alloc((size_t)N_EDGE * 4);
    float* s_src      = (float*)alloc((size_t)N_NODES * HEADS * 4);
    float* s_dst      = (float*)alloc((size_t)N_NODES * HEADS * 4);
    float* s_rel      = (float*)alloc((size_t)N_RELS * HEADS * 4);
    float* feat0      = (float*)alloc((size_t)N_NODES * HID * 4);
    float* hcA        = (float*)alloc((size_t)N_NODES * HID * 4);
    float* hcB        = (float*)alloc((size_t)N_NODES * HID * 4);
    float* res        = (float*)alloc((size_t)N_NODES * HID * 4);
    int*   kept_src   = (int*)alloc((size_t)N_NODES * HEADS * TOPK * 4);
    float* kept_w     = (float*)alloc((size_t)N_NODES * HEADS * TOPK * 4);
    int*   kept_cnt   = (int*)alloc((size_t)N_NODES * HEADS * 4);
    // total ~= 80 MB

    // ---- CSR by destination (edges are layer-invariant: build once) ----
    hipMemsetAsync(counts, 0, (size_t)N_NODES * 4, stream);
    hipMemsetAsync(cursor, 0, (size_t)N_NODES * 4, stream);
    hist_kernel<<<N_EDGE / 256, 256, 0, stream>>>(edge_dst, counts);
    scan_kernel<<<1, 1024, 0, stream>>>(counts, row_ptr);
    scatter_kernel<<<N_EDGE / 256, 256, 0, stream>>>(edge_src, edge_dst, edge_rel, row_ptr,
                                                     cursor, sorted_src, sorted_rel, sorted_eid);

    float* out_h = (float*)d_out;     // node rows; layer-1 output also lives here
    const float* h = ent_emb;
    const int nb_gemm = (N_NODES + 31) / 32;
    const int nb_nh   = (N_NODES * HEADS + 255) / 256;
    const int nb_elem = N_NODES * HID / 256;   // 12500, exact

    for (int l = 0; l < LAYERS; ++l) {
        const float* We = W_ent + (size_t)l * HID * HID;
        const float* Wr = W_rel + (size_t)l * HID * HID;
        const float* a  = attn_a + (size_t)l * 3 * HEADS * DH;
        const float* rW = res_W + (size_t)l * HID * HID;

        gemm64<<<nb_gemm, 256, 0, stream>>>(h, We, feat0, N_NODES);
        node_scores<<<nb_nh, 256, 0, stream>>>(feat0, a, s_src, s_dst);
        rel_scores<<<N_RELS, 64, 0, stream>>>(rel_emb, Wr, a + 2 * HEADS * DH, s_rel);
        topk_kernel<<<nb_nh, 256, 0, stream>>>(row_ptr, sorted_src, sorted_rel, sorted_eid,
                                               s_src, s_dst, s_rel, kept_src, kept_w, kept_cnt);
        hop_kernel<<<nb_elem, 256, 0, stream>>>(feat0, feat0, kept_src, kept_w, kept_cnt, hcA);
        hop_kernel<<<nb_elem, 256, 0, stream>>>(hcA, feat0, kept_src, kept_w, kept_cnt, hcB);
        hop_kernel<<<nb_elem, 256, 0, stream>>>(hcB, feat0, kept_src, kept_w, kept_cnt, hcA);
        gemm64<<<nb_gemm, 256, 0, stream>>>(h, rW, res, N_NODES);
        elu_kernel<<<nb_elem, 256, 0, stream>>>(hcA, res, out_h);
        h = out_h;
    }
    relout_kernel<<<N_RELS, 64, 0, stream>>>(rel_emb, fc_rel_w, (float*)d_out + (size_t)N_NODES * HID);
}